// Round 6
// baseline (553.425 us; speedup 1.0000x reference)
//
#include <hip/hip_runtime.h>
#include <cstdint>

#define SEQ     3120
#define SPAD    3200
#define DIM     1536
#define NQKV    4608
#define HEADS   12
#define HD      128
#define SPATIAL 390
#define EPSV    1e-5f
#define KVBLK   64
#define NTILES  49
#define NEGBIG  (-1e30f)
// 1/sqrt(128) * log2(e): attention scores computed in log2 domain
#define QSCALE  (0.08838834764831845f * 1.4426950408889634f)
#define THRL2   11.0f
#define CROW(r, hi) ((((r) & 3) + 8 * ((r) >> 2)) + 4 * (hi))

typedef unsigned short u16;
typedef short s16x8 __attribute__((ext_vector_type(8)));
typedef float f32x4 __attribute__((ext_vector_type(4)));
typedef float f32x16 __attribute__((ext_vector_type(16)));

__device__ __forceinline__ u16 f2bf(float f) {
  union { float f; unsigned u; } v; v.f = f;
  unsigned r = v.u + 0x7FFFu + ((v.u >> 16) & 1u);
  return (u16)(r >> 16);
}
__device__ __forceinline__ float bf2f(u16 b) {
  union { unsigned u; float f; } v; v.u = ((unsigned)b) << 16;
  return v.f;
}
__device__ __forceinline__ unsigned cvtpk(float lo, float hi) {
  unsigned r;
  asm("v_cvt_pk_bf16_f32 %0, %1, %2" : "=v"(r) : "v"(lo), "v"(hi));
  return r;
}
// async global->LDS, 16B per lane. LDS dest = wave-uniform base + lane*16.
__device__ __forceinline__ void gload16(const void* g, const void* l) {
  __builtin_amdgcn_global_load_lds(
      (const __attribute__((address_space(1))) unsigned*)g,
      (__attribute__((address_space(3))) unsigned*)(uintptr_t)l,
      16, 0, 0);
}

// ---------------- 1. convert x fp32 -> bf16, pad rows [SEQ,SPAD) with 0 ----
__global__ __launch_bounds__(256) void k_convert_x(const float* __restrict__ x,
                                                   u16* __restrict__ xb) {
  const int i = (blockIdx.x * 256 + threadIdx.x) * 4;
  if (i >= SPAD * DIM) return;
  const int row = i / DIM;
  float4 v = make_float4(0.f, 0.f, 0.f, 0.f);
  if (row < SEQ) v = *(const float4*)(x + i);
  const unsigned lo = (unsigned)f2bf(v.x) | ((unsigned)f2bf(v.y) << 16);
  const unsigned hi = (unsigned)f2bf(v.z) | ((unsigned)f2bf(v.w) << 16);
  *(uint2*)(xb + i) = make_uint2(lo, hi);
}

// ---------------- 2. transpose+convert weights: Wt[n][k] = W[k][n] ---------
__global__ __launch_bounds__(256) void k_transpose_w(
    const float* __restrict__ Wq, const float* __restrict__ Wk,
    const float* __restrict__ Wv, const float* __restrict__ Wo,
    u16* __restrict__ WtAll, u16* __restrict__ WoT) {
  const int wsel = blockIdx.z;
  const float* W = (wsel == 0) ? Wq : (wsel == 1) ? Wk : (wsel == 2) ? Wv : Wo;
  __shared__ float t[32][33];
  const int k0 = blockIdx.x * 32, n0 = blockIdx.y * 32;
  const int c = threadIdx.x & 31, r8 = threadIdx.x >> 5;
#pragma unroll
  for (int rr = 0; rr < 32; rr += 8)
    t[r8 + rr][c] = W[(size_t)(k0 + r8 + rr) * DIM + n0 + c];
  __syncthreads();
  u16* Wt = (wsel < 3) ? (WtAll + (size_t)wsel * DIM * DIM) : WoT;
#pragma unroll
  for (int rr = 0; rr < 32; rr += 8)
    Wt[(size_t)(n0 + r8 + rr) * DIM + k0 + c] = f2bf(t[c][r8 + rr]);
}

// ---------------- 3. concat bq|bk|bv ---------------------------------------
__global__ void k_biascat(const float* __restrict__ bq, const float* __restrict__ bk,
                          const float* __restrict__ bv, float* __restrict__ bcat) {
  const int i = blockIdx.x * 256 + threadIdx.x;
  if (i >= NQKV) return;
  bcat[i] = (i < DIM) ? bq[i] : (i < 2 * DIM) ? bk[i - DIM] : bv[i - 2 * DIM];
}

// ---------------- 4/8. bf16 MFMA GEMM: C[m][n] = sum_k A[m][k]*Bt[n][k]+bias
template <int OUT_BF16>
__global__ __launch_bounds__(256) void k_gemm(const u16* __restrict__ A,
                                              const u16* __restrict__ Bt,
                                              const float* __restrict__ bias,
                                              void* __restrict__ Cout,
                                              int N, int K, int storeMmax) {
  __shared__ short As[4096];  // [128][32]
  __shared__ short Bs[4096];  // [128][32]
  const int tid = threadIdx.x;
  const int lane = tid & 63, wv = tid >> 6;
  const int l15 = lane & 15, g = lane >> 4;
  const int brow = blockIdx.y * 128, bcol = blockIdx.x * 128;
  const int wr = wv >> 1, wc = wv & 1;

  const f32x4 z4 = {0.f, 0.f, 0.f, 0.f};
  f32x4 acc[4][4];
#pragma unroll
  for (int m = 0; m < 4; ++m)
#pragma unroll
    for (int n = 0; n < 4; ++n) acc[m][n] = z4;

  const int srow = wv * 16 + (lane >> 2);
  const int skk = (lane & 3) * 8;
  const u16* Ab = A + (size_t)(brow + srow) * K + skk;
  const u16* Bb = Bt + (size_t)(bcol + srow) * K + skk;
  short* AsW = As + wv * 512;
  short* BsW = Bs + wv * 512;
  const size_t step64 = (size_t)64 * K;

  for (int k0 = 0; k0 < K; k0 += 32) {
    __syncthreads();
    gload16(Ab + k0, AsW);
    gload16(Ab + k0 + step64, AsW + 2048);
    gload16(Bb + k0, BsW);
    gload16(Bb + k0 + step64, BsW + 2048);
    __syncthreads();
    s16x8 a[4], b[4];
#pragma unroll
    for (int m = 0; m < 4; ++m)
      a[m] = *(const s16x8*)&As[(wr * 64 + m * 16 + l15) * 32 + g * 8];
#pragma unroll
    for (int n = 0; n < 4; ++n)
      b[n] = *(const s16x8*)&Bs[(wc * 64 + n * 16 + l15) * 32 + g * 8];
#pragma unroll
    for (int m = 0; m < 4; ++m)
#pragma unroll
      for (int n = 0; n < 4; ++n)
        acc[m][n] = __builtin_amdgcn_mfma_f32_16x16x32_bf16(a[m], b[n], acc[m][n], 0, 0, 0);
  }

#pragma unroll
  for (int m = 0; m < 4; ++m) {
#pragma unroll
    for (int n = 0; n < 4; ++n) {
      const int cc = bcol + wc * 64 + n * 16 + l15;
      const float bb = bias[cc];
#pragma unroll
      for (int i = 0; i < 4; ++i) {
        const int r = brow + wr * 64 + m * 16 + g * 4 + i;
        if (r < storeMmax) {
          const float v = acc[m][n][i] + bb;
          if (OUT_BF16) ((u16*)Cout)[(size_t)r * N + cc] = f2bf(v);
          else          ((float*)Cout)[(size_t)r * N + cc] = v;
        }
      }
    }
  }
}

// ---------------- 5. per-token: rmsnorm + rope + biases --------------------
__global__ __launch_bounds__(256) void k_post(
    const u16* __restrict__ Pqkv, const float* __restrict__ freqs,
    const float* __restrict__ gq, const float* __restrict__ gk,
    const float* __restrict__ qkfb, const float* __restrict__ vfb,
    const float* __restrict__ vsb,
    u16* __restrict__ Qf, u16* __restrict__ Kf, u16* __restrict__ Vf) {
  const int s = blockIdx.x;
  const int t = threadIdx.x;
  const int fidx = s / SPATIAL;
  const int sp = s - fidx * SPATIAL;
  __shared__ float cs[64], sn[64];
  __shared__ float red[8];
  if (t < 64) {
    const float a = freqs[s * 64 + t];
    cs[t] = __cosf(a);
    sn[t] = __sinf(a);
  }
  const u16* qrow = Pqkv + (size_t)s * NQKV;
  const u16* krow = qrow + DIM;
  const u16* vrow = qrow + 2 * DIM;
  float sq = 0.f, sk = 0.f;
  for (int i = t; i < DIM; i += 256) {
    const float a = bf2f(qrow[i]); sq += a * a;
    const float b = bf2f(krow[i]); sk += b * b;
  }
#pragma unroll
  for (int off = 1; off < 64; off <<= 1) {
    sq += __shfl_xor(sq, off);
    sk += __shfl_xor(sk, off);
  }
  const int lane = t & 63, wv = t >> 6;
  if (lane == 0) { red[wv] = sq; red[wv + 4] = sk; }
  __syncthreads();
  sq = red[0] + red[1] + red[2] + red[3];
  sk = red[4] + red[5] + red[6] + red[7];
  const float rq = rsqrtf(sq * (1.0f / DIM) + EPSV);
  const float rk = rsqrtf(sk * (1.0f / DIM) + EPSV);
  for (int p = t; p < 768; p += 256) {
    const int d = 2 * p;
    const int pin = p & 63;
    const float c = cs[pin], s_ = sn[pin];
    const float bq0 = qkfb[fidx * DIM + d], bq1 = qkfb[fidx * DIM + d + 1];
    float xr = bf2f(qrow[d]) * rq * gq[d];
    float xi = bf2f(qrow[d + 1]) * rq * gq[d + 1];
    const float q0 = (xr * c - xi * s_ + bq0) * QSCALE;
    const float q1 = (xr * s_ + xi * c + bq1) * QSCALE;
    *(unsigned*)&Qf[(size_t)s * DIM + d] = (unsigned)f2bf(q0) | ((unsigned)f2bf(q1) << 16);
    xr = bf2f(krow[d]) * rk * gk[d];
    xi = bf2f(krow[d + 1]) * rk * gk[d + 1];
    const float k0 = xr * c - xi * s_ + bq0;
    const float k1 = xr * s_ + xi * c + bq1;
    *(unsigned*)&Kf[(size_t)s * DIM + d] = (unsigned)f2bf(k0) | ((unsigned)f2bf(k1) << 16);
    const float v0 = bf2f(vrow[d]) + vfb[fidx * DIM + d] + vsb[(size_t)sp * DIM + d];
    const float v1 = bf2f(vrow[d + 1]) + vfb[fidx * DIM + d + 1] + vsb[(size_t)sp * DIM + d + 1];
    *(unsigned*)&Vf[(size_t)s * DIM + d] = (unsigned)f2bf(v0) | ((unsigned)f2bf(v1) << 16);
  }
}

// ---------------- 6. V transpose: Vf[s][1536] -> Vt[dglob][SPAD] -----------
__global__ __launch_bounds__(256) void k_transpose_v(const u16* __restrict__ Vf,
                                                     u16* __restrict__ Vt) {
  __shared__ u16 tile[64][65];
  const int s0 = blockIdx.x * 64, c0 = blockIdx.y * 64;
  const int c = threadIdx.x & 63, r4 = threadIdx.x >> 6;
#pragma unroll
  for (int rr = 0; rr < 64; rr += 4) {
    const int s = s0 + r4 + rr;
    tile[r4 + rr][c] = (s < SEQ) ? Vf[(size_t)s * DIM + c0 + c] : (u16)0;
  }
  __syncthreads();
#pragma unroll
  for (int rr = 0; rr < 64; rr += 4) {
    const int dglob = c0 + r4 + rr;
    Vt[(size_t)dglob * SPAD + s0 + c] = tile[c][r4 + rr];
  }
}

// ---------------- 7. flash attention: 10 warps = 2 KV-groups x 5 q-warps ---
// grid (20, 12), 640 threads. Group g = (w>=5) owns KV tiles [g?25:0, g?49:25).
// Warp wq = w-5g owns q rows bx*160+wq*32..+31 (both groups cover SAME rows).
// Per-group double-buffered K/V LDS; warps wq<4 stage, wq==4 computes only.
// Final merge in-kernel: group 1 -> LDS (f32 O + m/s), group 0 merges+writes.
__global__ __launch_bounds__(640, 1) void k_attn(const u16* __restrict__ Qf,
                                                 const u16* __restrict__ Kf,
                                                 const u16* __restrict__ Vt,
                                                 u16* __restrict__ AttO) {
  __shared__ short KV[2][2][16384];  // [group][buf][K: [64key][16ch][8] | V: [128d][8ch][8]]
  const int h = blockIdx.y;
  const int tid = threadIdx.x;
  const int lane = tid & 63, w = tid >> 6;   // w in 0..9
  const int g = (w >= 5) ? 1 : 0, wq = w - g * 5;
  const int l31 = lane & 31, hi = lane >> 5;
  const int t0 = g ? 25 : 0;
  const int tend = g ? NTILES : 25;
  const int qrow = blockIdx.x * 160 + wq * 32 + l31;

  // Q B-frags: qb[s] = Q[qrow][16s + 8hi + j]
  s16x8 qb[8];
  {
    const u16* qp = Qf + (size_t)qrow * DIM + h * HD + hi * 8;
#pragma unroll
    for (int s = 0; s < 8; ++s) qb[s] = *(const s16x8*)(qp + s * 16);
  }

  f32x16 o[4];
#pragma unroll
  for (int d = 0; d < 4; ++d)
#pragma unroll
    for (int r = 0; r < 16; ++r) o[d][r] = 0.f;
  float m = NEGBIG, sl = 0.f;

  // staging pointers (warps wq=0..3 of each group stage that group's tile)
  const u16* Kp[4];
  const u16* Vp[4];
  if (wq < 4) {
#pragma unroll
    for (int it = 0; it < 4; ++it) {
      const int krow = wq * 16 + it * 4 + (lane >> 4);
      const int kch = (lane & 15) ^ (it * 4 + (lane >> 4));
      Kp[it] = Kf + (size_t)krow * DIM + h * HD + kch * 8;
      const int vrow = wq * 32 + it * 8 + (lane >> 3);
      const int vch = (lane & 7) ^ (lane >> 3);
      Vp[it] = Vt + (size_t)(h * HD + vrow) * SPAD + vch * 8;
    }
  }
  short* Ksb0 = &KV[g][0][0];
  short* Ksb1 = &KV[g][1][0];
  auto stage = [&](int T, int B) {
    const size_t kof = (size_t)T * KVBLK * DIM;
    const int vof = T * KVBLK;
    short* base = B ? Ksb1 : Ksb0;
#pragma unroll
    for (int it = 0; it < 4; ++it) {
      gload16(Kp[it] + kof, base + (wq * 16 + it * 4) * 128);
      gload16(Vp[it] + vof, base + 8192 + (wq * 32 + it * 8) * 64);
    }
  };

  if (wq < 4) {
    asm volatile("s_waitcnt vmcnt(0)" ::: "memory");  // drain qb loads
    stage(t0, 0);
  }

  for (int lt = 0; lt < 25; ++lt) {
    const int t = t0 + lt;
    const int b = lt & 1;
    const bool act = (t < tend);
    if (act && wq < 4) {
      if (t + 1 < tend) {
        stage(t + 1, b ^ 1);
        asm volatile("s_waitcnt vmcnt(8)" ::: "memory");
      } else {
        asm volatile("s_waitcnt vmcnt(0)" ::: "memory");
      }
    }
    __builtin_amdgcn_s_barrier();
    __builtin_amdgcn_sched_barrier(0);

    if (act) {
      const short* Ksb = b ? Ksb1 : Ksb0;
      const short* Vsb = Ksb + 8192;

      // S^T = K Q  (D[key][q]: col q = l31, row key = CROW(r,hi) per grp of 32)
      f32x16 st[2];
#pragma unroll
      for (int r = 0; r < 16; ++r) { st[0][r] = 0.f; st[1][r] = 0.f; }
      __builtin_amdgcn_s_setprio(1);
#pragma unroll
      for (int grp = 0; grp < 2; ++grp)
#pragma unroll
        for (int s = 0; s < 8; ++s) {
          const s16x8 ka = *(const s16x8*)&Ksb[(grp * 32 + l31) * 128 +
                                               (((2 * s + hi) ^ (lane & 15)) * 8)];
          st[grp] = __builtin_amdgcn_mfma_f32_32x32x16_bf16(ka, qb[s], st[grp], 0, 0, 0);
        }
      __builtin_amdgcn_s_setprio(0);

      // hoist V B-frags (ds_read latency hides under softmax VALU)
      s16x8 vb[4][4];
#pragma unroll
      for (int s = 0; s < 4; ++s)
#pragma unroll
        for (int d = 0; d < 4; ++d)
          vb[s][d] = *(const s16x8*)&Vsb[(d * 32 + l31) * 64 +
                                         (((2 * s + hi) ^ (lane & 7)) * 8)];

      if (t == NTILES - 1) {  // keys 3120..3135 invalid: grp1 regs 8..15
#pragma unroll
        for (int r = 8; r < 16; ++r) st[1][r] = NEGBIG;
      }
      // row max: 4 parallel chains + tree
      float a0 = st[0][0], a1 = st[0][1], a2 = st[0][2], a3 = st[0][3];
#pragma unroll
      for (int r = 4; r < 16; r += 4) {
        a0 = fmaxf(a0, st[0][r]);     a1 = fmaxf(a1, st[0][r + 1]);
        a2 = fmaxf(a2, st[0][r + 2]); a3 = fmaxf(a3, st[0][r + 3]);
      }
#pragma unroll
      for (int r = 0; r < 16; r += 4) {
        a0 = fmaxf(a0, st[1][r]);     a1 = fmaxf(a1, st[1][r + 1]);
        a2 = fmaxf(a2, st[1][r + 2]); a3 = fmaxf(a3, st[1][r + 3]);
      }
      float rm = fmaxf(fmaxf(a0, a1), fmaxf(a2, a3));
      rm = fmaxf(rm, __shfl_xor(rm, 32));

      if (__any(rm > m + THRL2)) {  // deferred rescale
        const float mn = fmaxf(m, rm);
        const float fac = exp2f(m - mn);
        m = mn;
        sl *= fac;
#pragma unroll
        for (int r = 0; r < 16; ++r) {
          const float fq = __shfl(fac, CROW(r, hi));
#pragma unroll
          for (int d = 0; d < 4; ++d) o[d][r] *= fq;
        }
      }
      // P = exp2(S - m): 4 partial sums, pack to bf16 pairs, partner exchange
      unsigned W[16], X[16];
      float p0s = 0.f, p1s = 0.f, p2s = 0.f, p3s = 0.f;
#pragma unroll
      for (int grp = 0; grp < 2; ++grp)
#pragma unroll
        for (int i = 0; i < 8; ++i) {
          const float p0 = exp2f(st[grp][2 * i] - m);
          const float p1 = exp2f(st[grp][2 * i + 1] - m);
          if (grp) { p2s += p0; p3s += p1; } else { p0s += p0; p1s += p1; }
          W[grp * 8 + i] = cvtpk(p0, p1);
        }
      sl += (p0s + p1s) + (p2s + p3s);
#pragma unroll
      for (int j = 0; j < 16; ++j) X[j] = __shfl_xor((int)W[j], 32);

      // O += P V
      __builtin_amdgcn_s_setprio(1);
#pragma unroll
      for (int s = 0; s < 4; ++s) {
        const int base = (s >> 1) * 8 + (s & 1) * 4;
        unsigned pw[4];
        pw[0] = hi ? X[base + 2] : W[base + 0];
        pw[1] = hi ? X[base + 3] : W[base + 1];
        pw[2] = hi ? W[base + 2] : X[base + 0];
        pw[3] = hi ? W[base + 3] : X[base + 1];
        const s16x8 pa = *(const s16x8*)pw;
#pragma unroll
        for (int d = 0; d < 4; ++d)
          o[d] = __builtin_amdgcn_mfma_f32_32x32x16_bf16(pa, vb[s][d], o[d], 0, 0, 0);
      }
      __builtin_amdgcn_s_setprio(0);
    }
    __builtin_amdgcn_s_barrier();
    __builtin_amdgcn_sched_barrier(0);
  }

  sl += __shfl_xor(sl, 32);

  // ---- in-kernel combine: group 1 -> LDS (f32), group 0 merges & writes ---
  __syncthreads();  // all K/V LDS traffic done; reuse LDS
  float* Of = (float*)&KV[0][0][0];                    // [160 q][128 d] f32 (80KB)
  float* msL = (float*)((char*)&KV[0][0][0] + 81920);  // [160 q][2]
  if (g == 1) {
    if (hi == 0) {
      msL[(wq * 32 + l31) * 2] = m;
      msL[(wq * 32 + l31) * 2 + 1] = sl;
    }
#pragma unroll
    for (int r = 0; r < 16; ++r) {
      const int rl = wq * 32 + CROW(r, hi);
#pragma unroll
      for (int d = 0; d < 4; ++d) Of[rl * 128 + d * 32 + l31] = o[d][r];
    }
  }
  __syncthreads();
  if (g == 0) {
#pragma unroll
    for (int r = 0; r < 16; ++r) {
      const int cr = CROW(r, hi);
      const int rl = wq * 32 + cr;
      const float mB = msL[rl * 2], slB = msL[rl * 2 + 1];
      const float mA = __shfl(m, cr), slA = __shfl(sl, cr);
      const float M = fmaxf(mA, mB);
      const float wA = exp2f(mA - M), wB = exp2f(mB - M);
      const float rden = 1.0f / (slA * wA + slB * wB);
      const int grow = blockIdx.x * 160 + rl;
      if (grow < SEQ) {
#pragma unroll
        for (int d = 0; d < 4; ++d) {
          const float val = (o[d][r] * wA + Of[rl * 128 + d * 32 + l31] * wB) * rden;
          AttO[(size_t)grow * DIM + h * HD + d * 32 + l31] = f2bf(val);
        }
      }
    }
  }
}

// ---------------------------------------------------------------------------
extern "C" void kernel_launch(void* const* d_in, const int* in_sizes, int n_in,
                              void* d_out, int out_size, void* d_ws, size_t ws_size,
                              hipStream_t stream) {
  const float* x    = (const float*)d_in[0];
  const float* freqs= (const float*)d_in[1];
  const float* Wq   = (const float*)d_in[2];
  const float* bq   = (const float*)d_in[3];
  const float* gq   = (const float*)d_in[4];
  const float* Wk   = (const float*)d_in[5];
  const float* bk   = (const float*)d_in[6];
  const float* gk   = (const float*)d_in[7];
  const float* Wv   = (const float*)d_in[8];
  const float* bv   = (const float*)d_in[9];
  const float* Wo   = (const float*)d_in[10];
  const float* bo   = (const float*)d_in[11];
  const float* qkfb = (const float*)d_in[12];
  const float* vfb  = (const float*)d_in[13];
  const float* vsb  = (const float*)d_in[14];

  if (ws_size < (size_t)87705600) return;

  char* ws = (char*)d_ws;
  u16*   xb    = (u16*)(ws);               // [3200][1536] bf16
  u16*   Vt    = (u16*)(ws);               // alias: xb dead after QKV GEMM
  u16*   WtAll = (u16*)(ws + 9830400);     // [4608][1536] bf16 (Wq|Wk|Wv)^T
  u16*   WoT   = (u16*)(ws + 23986176);    // [1536][1536] bf16 Wo^T
  float* bcat  = (float*)(ws + 28704768);  // [4608]
  u16*   Pqkv  = (u16*)(ws + 28723200);    // [3200][4608] bf16
  u16*   AttO  = (u16*)(ws + 28723200);    // alias: Pqkv dead after k_post
  u16*   Qf    = (u16*)(ws + 58214400);    // [3200][1536] bf16
  u16*   Kf    = (u16*)(ws + 68044800);    // [3200][1536] bf16
  u16*   Vf    = (u16*)(ws + 77875200);    // [3200][1536] bf16

  k_convert_x<<<4800, 256, 0, stream>>>(x, xb);
  k_transpose_w<<<dim3(48, 48, 4), 256, 0, stream>>>(Wq, Wk, Wv, Wo, WtAll, WoT);
  k_biascat<<<18, 256, 0, stream>>>(bq, bk, bv, bcat);
  k_gemm<1><<<dim3(36, 25), 256, 0, stream>>>(xb, WtAll, bcat, Pqkv, NQKV, DIM, SPAD);
  k_post<<<SEQ, 256, 0, stream>>>(Pqkv, freqs, gq, gk, qkfb, vfb, vsb, Qf, Kf, Vf);
  k_transpose_v<<<dim3(50, 24), 256, 0, stream>>>(Vf, Vt);
  k_attn<<<dim3(20, 12), 640, 0, stream>>>(Qf, Kf, Vt, AttO);
  k_gemm<0><<<dim3(12, 25), 256, 0, stream>>>(AttO, WoT, bo, d_out, DIM, DIM, SEQ);
}

// Round 7
// 552.829 us; speedup vs baseline: 1.0011x; 1.0011x over previous
//
#include <hip/hip_runtime.h>
#include <cstdint>

#define SEQ     3120
#define SPAD    3200
#define DIM     1536
#define NQKV    4608
#define HEADS   12
#define HD      128
#define SPATIAL 390
#define EPSV    1e-5f
#define KVBLK   64
#define NTILES  49
#define NEGBIG  (-1e30f)
// 1/sqrt(128) * log2(e): attention scores computed in log2 domain
#define QSCALE  (0.08838834764831845f * 1.4426950408889634f)
#define THRL2   11.0f
#define CROW(r, hi) ((((r) & 3) + 8 * ((r) >> 2)) + 4 * (hi))

typedef unsigned short u16;
typedef short s16x8 __attribute__((ext_vector_type(8)));
typedef float f32x4 __attribute__((ext_vector_type(4)));
typedef float f32x16 __attribute__((ext_vector_type(16)));

__device__ __forceinline__ u16 f2bf(float f) {
  union { float f; unsigned u; } v; v.f = f;
  unsigned r = v.u + 0x7FFFu + ((v.u >> 16) & 1u);
  return (u16)(r >> 16);
}
__device__ __forceinline__ float bf2f(u16 b) {
  union { unsigned u; float f; } v; v.u = ((unsigned)b) << 16;
  return v.f;
}
__device__ __forceinline__ unsigned cvtpk(float lo, float hi) {
  unsigned r;
  asm("v_cvt_pk_bf16_f32 %0, %1, %2" : "=v"(r) : "v"(lo), "v"(hi));
  return r;
}
// async global->LDS, 16B per lane. LDS dest = wave-uniform base + lane*16.
__device__ __forceinline__ void gload16(const void* g, const void* l) {
  __builtin_amdgcn_global_load_lds(
      (const __attribute__((address_space(1))) unsigned*)g,
      (__attribute__((address_space(3))) unsigned*)(uintptr_t)l,
      16, 0, 0);
}

// ---------------- 1. convert x fp32 -> bf16, pad rows [SEQ,SPAD) with 0 ----
__global__ __launch_bounds__(256) void k_convert_x(const float* __restrict__ x,
                                                   u16* __restrict__ xb) {
  const int i = (blockIdx.x * 256 + threadIdx.x) * 4;
  if (i >= SPAD * DIM) return;
  const int row = i / DIM;
  float4 v = make_float4(0.f, 0.f, 0.f, 0.f);
  if (row < SEQ) v = *(const float4*)(x + i);
  const unsigned lo = (unsigned)f2bf(v.x) | ((unsigned)f2bf(v.y) << 16);
  const unsigned hi = (unsigned)f2bf(v.z) | ((unsigned)f2bf(v.w) << 16);
  *(uint2*)(xb + i) = make_uint2(lo, hi);
}

// ---------------- 2. transpose+convert weights: Wt[n][k] = W[k][n] ---------
__global__ __launch_bounds__(256) void k_transpose_w(
    const float* __restrict__ Wq, const float* __restrict__ Wk,
    const float* __restrict__ Wv, const float* __restrict__ Wo,
    u16* __restrict__ WtAll, u16* __restrict__ WoT) {
  const int wsel = blockIdx.z;
  const float* W = (wsel == 0) ? Wq : (wsel == 1) ? Wk : (wsel == 2) ? Wv : Wo;
  __shared__ float t[32][33];
  const int k0 = blockIdx.x * 32, n0 = blockIdx.y * 32;
  const int c = threadIdx.x & 31, r8 = threadIdx.x >> 5;
#pragma unroll
  for (int rr = 0; rr < 32; rr += 8)
    t[r8 + rr][c] = W[(size_t)(k0 + r8 + rr) * DIM + n0 + c];
  __syncthreads();
  u16* Wt = (wsel < 3) ? (WtAll + (size_t)wsel * DIM * DIM) : WoT;
#pragma unroll
  for (int rr = 0; rr < 32; rr += 8)
    Wt[(size_t)(n0 + r8 + rr) * DIM + k0 + c] = f2bf(t[c][r8 + rr]);
}

// ---------------- 3. concat bq|bk|bv ---------------------------------------
__global__ void k_biascat(const float* __restrict__ bq, const float* __restrict__ bk,
                          const float* __restrict__ bv, float* __restrict__ bcat) {
  const int i = blockIdx.x * 256 + threadIdx.x;
  if (i >= NQKV) return;
  bcat[i] = (i < DIM) ? bq[i] : (i < 2 * DIM) ? bk[i - DIM] : bv[i - 2 * DIM];
}

// ---------------- 4/8. bf16 MFMA GEMM: C[m][n] = sum_k A[m][k]*Bt[n][k]+bias
template <int OUT_BF16>
__global__ __launch_bounds__(256) void k_gemm(const u16* __restrict__ A,
                                              const u16* __restrict__ Bt,
                                              const float* __restrict__ bias,
                                              void* __restrict__ Cout,
                                              int N, int K, int storeMmax) {
  __shared__ short As[4096];  // [128][32]
  __shared__ short Bs[4096];  // [128][32]
  const int tid = threadIdx.x;
  const int lane = tid & 63, wv = tid >> 6;
  const int l15 = lane & 15, g = lane >> 4;
  const int brow = blockIdx.y * 128, bcol = blockIdx.x * 128;
  const int wr = wv >> 1, wc = wv & 1;

  const f32x4 z4 = {0.f, 0.f, 0.f, 0.f};
  f32x4 acc[4][4];
#pragma unroll
  for (int m = 0; m < 4; ++m)
#pragma unroll
    for (int n = 0; n < 4; ++n) acc[m][n] = z4;

  const int srow = wv * 16 + (lane >> 2);
  const int skk = (lane & 3) * 8;
  const u16* Ab = A + (size_t)(brow + srow) * K + skk;
  const u16* Bb = Bt + (size_t)(bcol + srow) * K + skk;
  short* AsW = As + wv * 512;
  short* BsW = Bs + wv * 512;
  const size_t step64 = (size_t)64 * K;

  for (int k0 = 0; k0 < K; k0 += 32) {
    __syncthreads();
    gload16(Ab + k0, AsW);
    gload16(Ab + k0 + step64, AsW + 2048);
    gload16(Bb + k0, BsW);
    gload16(Bb + k0 + step64, BsW + 2048);
    __syncthreads();
    s16x8 a[4], b[4];
#pragma unroll
    for (int m = 0; m < 4; ++m)
      a[m] = *(const s16x8*)&As[(wr * 64 + m * 16 + l15) * 32 + g * 8];
#pragma unroll
    for (int n = 0; n < 4; ++n)
      b[n] = *(const s16x8*)&Bs[(wc * 64 + n * 16 + l15) * 32 + g * 8];
#pragma unroll
    for (int m = 0; m < 4; ++m)
#pragma unroll
      for (int n = 0; n < 4; ++n)
        acc[m][n] = __builtin_amdgcn_mfma_f32_16x16x32_bf16(a[m], b[n], acc[m][n], 0, 0, 0);
  }

#pragma unroll
  for (int m = 0; m < 4; ++m) {
#pragma unroll
    for (int n = 0; n < 4; ++n) {
      const int cc = bcol + wc * 64 + n * 16 + l15;
      const float bb = bias[cc];
#pragma unroll
      for (int i = 0; i < 4; ++i) {
        const int r = brow + wr * 64 + m * 16 + g * 4 + i;
        if (r < storeMmax) {
          const float v = acc[m][n][i] + bb;
          if (OUT_BF16) ((u16*)Cout)[(size_t)r * N + cc] = f2bf(v);
          else          ((float*)Cout)[(size_t)r * N + cc] = v;
        }
      }
    }
  }
}

// ---------------- 5. per-token: rmsnorm + rope + biases --------------------
__global__ __launch_bounds__(256) void k_post(
    const u16* __restrict__ Pqkv, const float* __restrict__ freqs,
    const float* __restrict__ gq, const float* __restrict__ gk,
    const float* __restrict__ qkfb, const float* __restrict__ vfb,
    const float* __restrict__ vsb,
    u16* __restrict__ Qf, u16* __restrict__ Kf, u16* __restrict__ Vf) {
  const int s = blockIdx.x;
  const int t = threadIdx.x;
  const int fidx = s / SPATIAL;
  const int sp = s - fidx * SPATIAL;
  __shared__ float cs[64], sn[64];
  __shared__ float red[8];
  if (t < 64) {
    const float a = freqs[s * 64 + t];
    cs[t] = __cosf(a);
    sn[t] = __sinf(a);
  }
  const u16* qrow = Pqkv + (size_t)s * NQKV;
  const u16* krow = qrow + DIM;
  const u16* vrow = qrow + 2 * DIM;
  float sq = 0.f, sk = 0.f;
  for (int i = t; i < DIM; i += 256) {
    const float a = bf2f(qrow[i]); sq += a * a;
    const float b = bf2f(krow[i]); sk += b * b;
  }
#pragma unroll
  for (int off = 1; off < 64; off <<= 1) {
    sq += __shfl_xor(sq, off);
    sk += __shfl_xor(sk, off);
  }
  const int lane = t & 63, wv = t >> 6;
  if (lane == 0) { red[wv] = sq; red[wv + 4] = sk; }
  __syncthreads();
  sq = red[0] + red[1] + red[2] + red[3];
  sk = red[4] + red[5] + red[6] + red[7];
  const float rq = rsqrtf(sq * (1.0f / DIM) + EPSV);
  const float rk = rsqrtf(sk * (1.0f / DIM) + EPSV);
  for (int p = t; p < 768; p += 256) {
    const int d = 2 * p;
    const int pin = p & 63;
    const float c = cs[pin], s_ = sn[pin];
    const float bq0 = qkfb[fidx * DIM + d], bq1 = qkfb[fidx * DIM + d + 1];
    float xr = bf2f(qrow[d]) * rq * gq[d];
    float xi = bf2f(qrow[d + 1]) * rq * gq[d + 1];
    const float q0 = (xr * c - xi * s_ + bq0) * QSCALE;
    const float q1 = (xr * s_ + xi * c + bq1) * QSCALE;
    *(unsigned*)&Qf[(size_t)s * DIM + d] = (unsigned)f2bf(q0) | ((unsigned)f2bf(q1) << 16);
    xr = bf2f(krow[d]) * rk * gk[d];
    xi = bf2f(krow[d + 1]) * rk * gk[d + 1];
    const float k0 = xr * c - xi * s_ + bq0;
    const float k1 = xr * s_ + xi * c + bq1;
    *(unsigned*)&Kf[(size_t)s * DIM + d] = (unsigned)f2bf(k0) | ((unsigned)f2bf(k1) << 16);
    const float v0 = bf2f(vrow[d]) + vfb[fidx * DIM + d] + vsb[(size_t)sp * DIM + d];
    const float v1 = bf2f(vrow[d + 1]) + vfb[fidx * DIM + d + 1] + vsb[(size_t)sp * DIM + d + 1];
    *(unsigned*)&Vf[(size_t)s * DIM + d] = (unsigned)f2bf(v0) | ((unsigned)f2bf(v1) << 16);
  }
}

// ---------------- 6. V transpose: Vf[s][1536] -> Vt[dglob][SPAD] -----------
__global__ __launch_bounds__(256) void k_transpose_v(const u16* __restrict__ Vf,
                                                     u16* __restrict__ Vt) {
  __shared__ u16 tile[64][65];
  const int s0 = blockIdx.x * 64, c0 = blockIdx.y * 64;
  const int c = threadIdx.x & 63, r4 = threadIdx.x >> 6;
#pragma unroll
  for (int rr = 0; rr < 64; rr += 4) {
    const int s = s0 + r4 + rr;
    tile[r4 + rr][c] = (s < SEQ) ? Vf[(size_t)s * DIM + c0 + c] : (u16)0;
  }
  __syncthreads();
#pragma unroll
  for (int rr = 0; rr < 64; rr += 4) {
    const int dglob = c0 + r4 + rr;
    Vt[(size_t)dglob * SPAD + s0 + c] = tile[c][r4 + rr];
  }
}

// ---------------- 7. flash attention: 10 warps = 2 KV-groups x 5 q-warps ---
// grid (20, 12), 640 threads. Group g = (w>=5) owns KV tiles [g?25:0, g?49:25).
// Warp wq = w-5g owns q rows bx*160+wq*32..+31 (both groups cover SAME rows).
// Per-group double-buffered K/V LDS; warps wq<4 stage, wq==4 computes only.
// Final merge in-kernel: group 1 -> LDS (f32 O + m/s), group 0 merges+writes.
// waves_per_eu(3): VGPR cap 512/3=168 >= ~150 needed. R6's default heuristic
// capped at 84 -> accumulator spill -> 719MB scratch HBM traffic, 2.7x slower.
__global__ __launch_bounds__(640)
__attribute__((amdgpu_waves_per_eu(3)))
void k_attn(const u16* __restrict__ Qf,
            const u16* __restrict__ Kf,
            const u16* __restrict__ Vt,
            u16* __restrict__ AttO) {
  __shared__ short KV[2][2][16384];  // [group][buf][K: [64key][16ch][8] | V: [128d][8ch][8]]
  const int h = blockIdx.y;
  const int tid = threadIdx.x;
  const int lane = tid & 63, w = tid >> 6;   // w in 0..9
  const int g = (w >= 5) ? 1 : 0, wq = w - g * 5;
  const int l31 = lane & 31, hi = lane >> 5;
  const int t0 = g ? 25 : 0;
  const int tend = g ? NTILES : 25;
  const int qrow = blockIdx.x * 160 + wq * 32 + l31;

  // Q B-frags: qb[s] = Q[qrow][16s + 8hi + j]
  s16x8 qb[8];
  {
    const u16* qp = Qf + (size_t)qrow * DIM + h * HD + hi * 8;
#pragma unroll
    for (int s = 0; s < 8; ++s) qb[s] = *(const s16x8*)(qp + s * 16);
  }

  f32x16 o[4];
#pragma unroll
  for (int d = 0; d < 4; ++d)
#pragma unroll
    for (int r = 0; r < 16; ++r) o[d][r] = 0.f;
  float m = NEGBIG, sl = 0.f;

  // staging pointers (warps wq=0..3 of each group stage that group's tile)
  const u16* Kp[4];
  const u16* Vp[4];
  if (wq < 4) {
#pragma unroll
    for (int it = 0; it < 4; ++it) {
      const int krow = wq * 16 + it * 4 + (lane >> 4);
      const int kch = (lane & 15) ^ (it * 4 + (lane >> 4));
      Kp[it] = Kf + (size_t)krow * DIM + h * HD + kch * 8;
      const int vrow = wq * 32 + it * 8 + (lane >> 3);
      const int vch = (lane & 7) ^ (lane >> 3);
      Vp[it] = Vt + (size_t)(h * HD + vrow) * SPAD + vch * 8;
    }
  }
  short* Ksb0 = &KV[g][0][0];
  short* Ksb1 = &KV[g][1][0];
  auto stage = [&](int T, int B) {
    const size_t kof = (size_t)T * KVBLK * DIM;
    const int vof = T * KVBLK;
    short* base = B ? Ksb1 : Ksb0;
#pragma unroll
    for (int it = 0; it < 4; ++it) {
      gload16(Kp[it] + kof, base + (wq * 16 + it * 4) * 128);
      gload16(Vp[it] + vof, base + 8192 + (wq * 32 + it * 8) * 64);
    }
  };

  if (wq < 4) {
    asm volatile("s_waitcnt vmcnt(0)" ::: "memory");  // drain qb loads
    stage(t0, 0);
  }

  for (int lt = 0; lt < 25; ++lt) {
    const int t = t0 + lt;
    const int b = lt & 1;
    const bool act = (t < tend);
    if (act && wq < 4) {
      if (t + 1 < tend) {
        stage(t + 1, b ^ 1);
        asm volatile("s_waitcnt vmcnt(8)" ::: "memory");
      } else {
        asm volatile("s_waitcnt vmcnt(0)" ::: "memory");
      }
    }
    __builtin_amdgcn_s_barrier();
    __builtin_amdgcn_sched_barrier(0);

    if (act) {
      const short* Ksb = b ? Ksb1 : Ksb0;
      const short* Vsb = Ksb + 8192;

      // S^T = K Q  (D[key][q]: col q = l31, row key = CROW(r,hi) per grp of 32)
      f32x16 st[2];
#pragma unroll
      for (int r = 0; r < 16; ++r) { st[0][r] = 0.f; st[1][r] = 0.f; }
      __builtin_amdgcn_s_setprio(1);
#pragma unroll
      for (int grp = 0; grp < 2; ++grp)
#pragma unroll
        for (int s = 0; s < 8; ++s) {
          const s16x8 ka = *(const s16x8*)&Ksb[(grp * 32 + l31) * 128 +
                                               (((2 * s + hi) ^ (lane & 15)) * 8)];
          st[grp] = __builtin_amdgcn_mfma_f32_32x32x16_bf16(ka, qb[s], st[grp], 0, 0, 0);
        }
      __builtin_amdgcn_s_setprio(0);

      // hoist V B-frags (ds_read latency hides under softmax VALU)
      s16x8 vb[4][4];
#pragma unroll
      for (int s = 0; s < 4; ++s)
#pragma unroll
        for (int d = 0; d < 4; ++d)
          vb[s][d] = *(const s16x8*)&Vsb[(d * 32 + l31) * 64 +
                                         (((2 * s + hi) ^ (lane & 7)) * 8)];

      if (t == NTILES - 1) {  // keys 3120..3135 invalid: grp1 regs 8..15
#pragma unroll
        for (int r = 8; r < 16; ++r) st[1][r] = NEGBIG;
      }
      // row max: 4 parallel chains + tree
      float a0 = st[0][0], a1 = st[0][1], a2 = st[0][2], a3 = st[0][3];
#pragma unroll
      for (int r = 4; r < 16; r += 4) {
        a0 = fmaxf(a0, st[0][r]);     a1 = fmaxf(a1, st[0][r + 1]);
        a2 = fmaxf(a2, st[0][r + 2]); a3 = fmaxf(a3, st[0][r + 3]);
      }
#pragma unroll
      for (int r = 0; r < 16; r += 4) {
        a0 = fmaxf(a0, st[1][r]);     a1 = fmaxf(a1, st[1][r + 1]);
        a2 = fmaxf(a2, st[1][r + 2]); a3 = fmaxf(a3, st[1][r + 3]);
      }
      float rm = fmaxf(fmaxf(a0, a1), fmaxf(a2, a3));
      rm = fmaxf(rm, __shfl_xor(rm, 32));

      if (__any(rm > m + THRL2)) {  // deferred rescale
        const float mn = fmaxf(m, rm);
        const float fac = exp2f(m - mn);
        m = mn;
        sl *= fac;
#pragma unroll
        for (int r = 0; r < 16; ++r) {
          const float fq = __shfl(fac, CROW(r, hi));
#pragma unroll
          for (int d = 0; d < 4; ++d) o[d][r] *= fq;
        }
      }
      // P = exp2(S - m): 4 partial sums, pack to bf16 pairs, partner exchange
      unsigned W[16], X[16];
      float p0s = 0.f, p1s = 0.f, p2s = 0.f, p3s = 0.f;
#pragma unroll
      for (int grp = 0; grp < 2; ++grp)
#pragma unroll
        for (int i = 0; i < 8; ++i) {
          const float p0 = exp2f(st[grp][2 * i] - m);
          const float p1 = exp2f(st[grp][2 * i + 1] - m);
          if (grp) { p2s += p0; p3s += p1; } else { p0s += p0; p1s += p1; }
          W[grp * 8 + i] = cvtpk(p0, p1);
        }
      sl += (p0s + p1s) + (p2s + p3s);
#pragma unroll
      for (int j = 0; j < 16; ++j) X[j] = __shfl_xor((int)W[j], 32);

      // O += P V
      __builtin_amdgcn_s_setprio(1);
#pragma unroll
      for (int s = 0; s < 4; ++s) {
        const int base = (s >> 1) * 8 + (s & 1) * 4;
        unsigned pw[4];
        pw[0] = hi ? X[base + 2] : W[base + 0];
        pw[1] = hi ? X[base + 3] : W[base + 1];
        pw[2] = hi ? W[base + 2] : X[base + 0];
        pw[3] = hi ? W[base + 3] : X[base + 1];
        const s16x8 pa = *(const s16x8*)pw;
#pragma unroll
        for (int d = 0; d < 4; ++d)
          o[d] = __builtin_amdgcn_mfma_f32_32x32x16_bf16(pa, vb[s][d], o[d], 0, 0, 0);
      }
      __builtin_amdgcn_s_setprio(0);
    }
    __builtin_amdgcn_s_barrier();
    __builtin_amdgcn_sched_barrier(0);
  }

  sl += __shfl_xor(sl, 32);

  // ---- in-kernel combine: group 1 -> LDS (f32), group 0 merges & writes ---
  __syncthreads();  // all K/V LDS traffic done; reuse LDS
  float* Of = (float*)&KV[0][0][0];                    // [160 q][128 d] f32 (80KB)
  float* msL = (float*)((char*)&KV[0][0][0] + 81920);  // [160 q][2]
  if (g == 1) {
    if (hi == 0) {
      msL[(wq * 32 + l31) * 2] = m;
      msL[(wq * 32 + l31) * 2 + 1] = sl;
    }
#pragma unroll
    for (int r = 0; r < 16; ++r) {
      const int rl = wq * 32 + CROW(r, hi);
#pragma unroll
      for (int d = 0; d < 4; ++d) Of[rl * 128 + d * 32 + l31] = o[d][r];
    }
  }
  __syncthreads();
  if (g == 0) {
#pragma unroll
    for (int r = 0; r < 16; ++r) {
      const int cr = CROW(r, hi);
      const int rl = wq * 32 + cr;
      const float mB = msL[rl * 2], slB = msL[rl * 2 + 1];
      const float mA = __shfl(m, cr), slA = __shfl(sl, cr);
      const float M = fmaxf(mA, mB);
      const float wA = exp2f(mA - M), wB = exp2f(mB - M);
      const float rden = 1.0f / (slA * wA + slB * wB);
      const int grow = blockIdx.x * 160 + rl;
      if (grow < SEQ) {
#pragma unroll
        for (int d = 0; d < 4; ++d) {
          const float val = (o[d][r] * wA + Of[rl * 128 + d * 32 + l31] * wB) * rden;
          AttO[(size_t)grow * DIM + h * HD + d * 32 + l31] = f2bf(val);
        }
      }
    }
  }
}

// ---------------------------------------------------------------------------
extern "C" void kernel_launch(void* const* d_in, const int* in_sizes, int n_in,
                              void* d_out, int out_size, void* d_ws, size_t ws_size,
                              hipStream_t stream) {
  const float* x    = (const float*)d_in[0];
  const float* freqs= (const float*)d_in[1];
  const float* Wq   = (const float*)d_in[2];
  const float* bq   = (const float*)d_in[3];
  const float* gq   = (const float*)d_in[4];
  const float* Wk   = (const float*)d_in[5];
  const float* bk   = (const float*)d_in[6];
  const float* gk   = (const float*)d_in[7];
  const float* Wv   = (const float*)d_in[8];
  const float* bv   = (const float*)d_in[9];
  const float* Wo   = (const float*)d_in[10];
  const float* bo   = (const float*)d_in[11];
  const float* qkfb = (const float*)d_in[12];
  const float* vfb  = (const float*)d_in[13];
  const float* vsb  = (const float*)d_in[14];

  if (ws_size < (size_t)87705600) return;

  char* ws = (char*)d_ws;
  u16*   xb    = (u16*)(ws);               // [3200][1536] bf16
  u16*   Vt    = (u16*)(ws);               // alias: xb dead after QKV GEMM
  u16*   WtAll = (u16*)(ws + 9830400);     // [4608][1536] bf16 (Wq|Wk|Wv)^T
  u16*   WoT   = (u16*)(ws + 23986176);    // [1536][1536] bf16 Wo^T
  float* bcat  = (float*)(ws + 28704768);  // [4608]
  u16*   Pqkv  = (u16*)(ws + 28723200);    // [3200][4608] bf16
  u16*   AttO  = (u16*)(ws + 28723200);    // alias: Pqkv dead after k_post
  u16*   Qf    = (u16*)(ws + 58214400);    // [3200][1536] bf16
  u16*   Kf    = (u16*)(ws + 68044800);    // [3200][1536] bf16
  u16*   Vf    = (u16*)(ws + 77875200);    // [3200][1536] bf16

  k_convert_x<<<4800, 256, 0, stream>>>(x, xb);
  k_transpose_w<<<dim3(48, 48, 4), 256, 0, stream>>>(Wq, Wk, Wv, Wo, WtAll, WoT);
  k_biascat<<<18, 256, 0, stream>>>(bq, bk, bv, bcat);
  k_gemm<1><<<dim3(36, 25), 256, 0, stream>>>(xb, WtAll, bcat, Pqkv, NQKV, DIM, SPAD);
  k_post<<<SEQ, 256, 0, stream>>>(Pqkv, freqs, gq, gk, qkfb, vfb, vsb, Qf, Kf, Vf);
  k_transpose_v<<<dim3(50, 24), 256, 0, stream>>>(Vf, Vt);
  k_attn<<<dim3(20, 12), 640, 0, stream>>>(Qf, Kf, Vt, AttO);
  k_gemm<0><<<dim3(12, 25), 256, 0, stream>>>(AttO, WoT, bo, d_out, DIM, DIM, SEQ);
}

// Round 8
// 282.914 us; speedup vs baseline: 1.9562x; 1.9541x over previous
//
#include <hip/hip_runtime.h>
#include <cstdint>

#define SEQ     3120
#define SPAD    3200
#define DIM     1536
#define NQKV    4608
#define HEADS   12
#define HD      128
#define SPATIAL 390
#define EPSV    1e-5f
#define KVBLK   64
#define NTILES  49
#define NEGBIG  (-1e30f)
// 1/sqrt(128) * log2(e): attention scores computed in log2 domain.
// Softmax uses a FIXED scale (no running max): |s| <= ~12 in log2 domain, so
// exp2(s) <= 4096 and sum <= ~1e7 -- safely inside fp32; softmax is exactly
// scale-invariant, and bf16 relative precision is scale-free.
#define QSCALE  (0.08838834764831845f * 1.4426950408889634f)
#define CROW(r, hi) ((((r) & 3) + 8 * ((r) >> 2)) + 4 * (hi))

typedef unsigned short u16;
typedef short s16x8 __attribute__((ext_vector_type(8)));
typedef float f32x4 __attribute__((ext_vector_type(4)));
typedef float f32x16 __attribute__((ext_vector_type(16)));

__device__ __forceinline__ u16 f2bf(float f) {
  union { float f; unsigned u; } v; v.f = f;
  unsigned r = v.u + 0x7FFFu + ((v.u >> 16) & 1u);
  return (u16)(r >> 16);
}
__device__ __forceinline__ float bf2f(u16 b) {
  union { unsigned u; float f; } v; v.u = ((unsigned)b) << 16;
  return v.f;
}
__device__ __forceinline__ unsigned cvtpk(float lo, float hi) {
  unsigned r;
  asm("v_cvt_pk_bf16_f32 %0, %1, %2" : "=v"(r) : "v"(lo), "v"(hi));
  return r;
}
// async global->LDS, 16B per lane. LDS dest = wave-uniform base + lane*16.
__device__ __forceinline__ void gload16(const void* g, const void* l) {
  __builtin_amdgcn_global_load_lds(
      (const __attribute__((address_space(1))) unsigned*)g,
      (__attribute__((address_space(3))) unsigned*)(uintptr_t)l,
      16, 0, 0);
}

// ---------------- 1. convert x fp32 -> bf16, pad rows [SEQ,SPAD) with 0 ----
__global__ __launch_bounds__(256) void k_convert_x(const float* __restrict__ x,
                                                   u16* __restrict__ xb) {
  const int i = (blockIdx.x * 256 + threadIdx.x) * 4;
  if (i >= SPAD * DIM) return;
  const int row = i / DIM;
  float4 v = make_float4(0.f, 0.f, 0.f, 0.f);
  if (row < SEQ) v = *(const float4*)(x + i);
  const unsigned lo = (unsigned)f2bf(v.x) | ((unsigned)f2bf(v.y) << 16);
  const unsigned hi = (unsigned)f2bf(v.z) | ((unsigned)f2bf(v.w) << 16);
  *(uint2*)(xb + i) = make_uint2(lo, hi);
}

// ---------------- 2. transpose+convert weights: Wt[n][k] = W[k][n] ---------
__global__ __launch_bounds__(256) void k_transpose_w(
    const float* __restrict__ Wq, const float* __restrict__ Wk,
    const float* __restrict__ Wv, const float* __restrict__ Wo,
    u16* __restrict__ WtAll, u16* __restrict__ WoT) {
  const int wsel = blockIdx.z;
  const float* W = (wsel == 0) ? Wq : (wsel == 1) ? Wk : (wsel == 2) ? Wv : Wo;
  __shared__ float t[32][33];
  const int k0 = blockIdx.x * 32, n0 = blockIdx.y * 32;
  const int c = threadIdx.x & 31, r8 = threadIdx.x >> 5;
#pragma unroll
  for (int rr = 0; rr < 32; rr += 8)
    t[r8 + rr][c] = W[(size_t)(k0 + r8 + rr) * DIM + n0 + c];
  __syncthreads();
  u16* Wt = (wsel < 3) ? (WtAll + (size_t)wsel * DIM * DIM) : WoT;
#pragma unroll
  for (int rr = 0; rr < 32; rr += 8)
    Wt[(size_t)(n0 + r8 + rr) * DIM + k0 + c] = f2bf(t[c][r8 + rr]);
}

// ---------------- 3. concat bq|bk|bv ---------------------------------------
__global__ void k_biascat(const float* __restrict__ bq, const float* __restrict__ bk,
                          const float* __restrict__ bv, float* __restrict__ bcat) {
  const int i = blockIdx.x * 256 + threadIdx.x;
  if (i >= NQKV) return;
  bcat[i] = (i < DIM) ? bq[i] : (i < 2 * DIM) ? bk[i - DIM] : bv[i - 2 * DIM];
}

// ---------------- 4/8. bf16 MFMA GEMM: C[m][n] = sum_k A[m][k]*Bt[n][k]+bias
template <int OUT_BF16>
__global__ __launch_bounds__(256) void k_gemm(const u16* __restrict__ A,
                                              const u16* __restrict__ Bt,
                                              const float* __restrict__ bias,
                                              void* __restrict__ Cout,
                                              int N, int K, int storeMmax) {
  __shared__ short As[4096];  // [128][32]
  __shared__ short Bs[4096];  // [128][32]
  const int tid = threadIdx.x;
  const int lane = tid & 63, wv = tid >> 6;
  const int l15 = lane & 15, g = lane >> 4;
  const int brow = blockIdx.y * 128, bcol = blockIdx.x * 128;
  const int wr = wv >> 1, wc = wv & 1;

  const f32x4 z4 = {0.f, 0.f, 0.f, 0.f};
  f32x4 acc[4][4];
#pragma unroll
  for (int m = 0; m < 4; ++m)
#pragma unroll
    for (int n = 0; n < 4; ++n) acc[m][n] = z4;

  const int srow = wv * 16 + (lane >> 2);
  const int skk = (lane & 3) * 8;
  const u16* Ab = A + (size_t)(brow + srow) * K + skk;
  const u16* Bb = Bt + (size_t)(bcol + srow) * K + skk;
  short* AsW = As + wv * 512;
  short* BsW = Bs + wv * 512;
  const size_t step64 = (size_t)64 * K;

  for (int k0 = 0; k0 < K; k0 += 32) {
    __syncthreads();
    gload16(Ab + k0, AsW);
    gload16(Ab + k0 + step64, AsW + 2048);
    gload16(Bb + k0, BsW);
    gload16(Bb + k0 + step64, BsW + 2048);
    __syncthreads();
    s16x8 a[4], b[4];
#pragma unroll
    for (int m = 0; m < 4; ++m)
      a[m] = *(const s16x8*)&As[(wr * 64 + m * 16 + l15) * 32 + g * 8];
#pragma unroll
    for (int n = 0; n < 4; ++n)
      b[n] = *(const s16x8*)&Bs[(wc * 64 + n * 16 + l15) * 32 + g * 8];
#pragma unroll
    for (int m = 0; m < 4; ++m)
#pragma unroll
      for (int n = 0; n < 4; ++n)
        acc[m][n] = __builtin_amdgcn_mfma_f32_16x16x32_bf16(a[m], b[n], acc[m][n], 0, 0, 0);
  }

#pragma unroll
  for (int m = 0; m < 4; ++m) {
#pragma unroll
    for (int n = 0; n < 4; ++n) {
      const int cc = bcol + wc * 64 + n * 16 + l15;
      const float bb = bias[cc];
#pragma unroll
      for (int i = 0; i < 4; ++i) {
        const int r = brow + wr * 64 + m * 16 + g * 4 + i;
        if (r < storeMmax) {
          const float v = acc[m][n][i] + bb;
          if (OUT_BF16) ((u16*)Cout)[(size_t)r * N + cc] = f2bf(v);
          else          ((float*)Cout)[(size_t)r * N + cc] = v;
        }
      }
    }
  }
}

// ---------------- 5. per-token: rmsnorm + rope + biases --------------------
__global__ __launch_bounds__(256) void k_post(
    const u16* __restrict__ Pqkv, const float* __restrict__ freqs,
    const float* __restrict__ gq, const float* __restrict__ gk,
    const float* __restrict__ qkfb, const float* __restrict__ vfb,
    const float* __restrict__ vsb,
    u16* __restrict__ Qf, u16* __restrict__ Kf, u16* __restrict__ Vf) {
  const int s = blockIdx.x;
  const int t = threadIdx.x;
  const int fidx = s / SPATIAL;
  const int sp = s - fidx * SPATIAL;
  __shared__ float cs[64], sn[64];
  __shared__ float red[8];
  if (t < 64) {
    const float a = freqs[s * 64 + t];
    cs[t] = __cosf(a);
    sn[t] = __sinf(a);
  }
  const u16* qrow = Pqkv + (size_t)s * NQKV;
  const u16* krow = qrow + DIM;
  const u16* vrow = qrow + 2 * DIM;
  float sq = 0.f, sk = 0.f;
  for (int i = t; i < DIM; i += 256) {
    const float a = bf2f(qrow[i]); sq += a * a;
    const float b = bf2f(krow[i]); sk += b * b;
  }
#pragma unroll
  for (int off = 1; off < 64; off <<= 1) {
    sq += __shfl_xor(sq, off);
    sk += __shfl_xor(sk, off);
  }
  const int lane = t & 63, wv = t >> 6;
  if (lane == 0) { red[wv] = sq; red[wv + 4] = sk; }
  __syncthreads();
  sq = red[0] + red[1] + red[2] + red[3];
  sk = red[4] + red[5] + red[6] + red[7];
  const float rq = rsqrtf(sq * (1.0f / DIM) + EPSV);
  const float rk = rsqrtf(sk * (1.0f / DIM) + EPSV);
  for (int p = t; p < 768; p += 256) {
    const int d = 2 * p;
    const int pin = p & 63;
    const float c = cs[pin], s_ = sn[pin];
    const float bq0 = qkfb[fidx * DIM + d], bq1 = qkfb[fidx * DIM + d + 1];
    float xr = bf2f(qrow[d]) * rq * gq[d];
    float xi = bf2f(qrow[d + 1]) * rq * gq[d + 1];
    const float q0 = (xr * c - xi * s_ + bq0) * QSCALE;
    const float q1 = (xr * s_ + xi * c + bq1) * QSCALE;
    *(unsigned*)&Qf[(size_t)s * DIM + d] = (unsigned)f2bf(q0) | ((unsigned)f2bf(q1) << 16);
    xr = bf2f(krow[d]) * rk * gk[d];
    xi = bf2f(krow[d + 1]) * rk * gk[d + 1];
    const float k0 = xr * c - xi * s_ + bq0;
    const float k1 = xr * s_ + xi * c + bq1;
    *(unsigned*)&Kf[(size_t)s * DIM + d] = (unsigned)f2bf(k0) | ((unsigned)f2bf(k1) << 16);
    const float v0 = bf2f(vrow[d]) + vfb[fidx * DIM + d] + vsb[(size_t)sp * DIM + d];
    const float v1 = bf2f(vrow[d + 1]) + vfb[fidx * DIM + d + 1] + vsb[(size_t)sp * DIM + d + 1];
    *(unsigned*)&Vf[(size_t)s * DIM + d] = (unsigned)f2bf(v0) | ((unsigned)f2bf(v1) << 16);
  }
}

// ---------------- 6. V transpose: Vf[s][1536] -> Vt[dglob][SPAD] -----------
__global__ __launch_bounds__(256) void k_transpose_v(const u16* __restrict__ Vf,
                                                     u16* __restrict__ Vt) {
  __shared__ u16 tile[64][65];
  const int s0 = blockIdx.x * 64, c0 = blockIdx.y * 64;
  const int c = threadIdx.x & 63, r4 = threadIdx.x >> 6;
#pragma unroll
  for (int rr = 0; rr < 64; rr += 4) {
    const int s = s0 + r4 + rr;
    tile[r4 + rr][c] = (s < SEQ) ? Vf[(size_t)s * DIM + c0 + c] : (u16)0;
  }
  __syncthreads();
#pragma unroll
  for (int rr = 0; rr < 64; rr += 4) {
    const int dglob = c0 + r4 + rr;
    Vt[(size_t)dglob * SPAD + s0 + c] = tile[c][r4 + rr];
  }
}

// ---------------- 7. flash attention, 32x32 MFMA, swapped QK^T -------------
// grid (20, 12), 320 threads = 5 warps (R3 structure: 128 VGPR, no spill).
// Warp w owns q rows bx*160+w*32..+31; lane owns q-row l&31 (partner lane^32).
// K LDS [64][128] chunk^=(row&15); V^T LDS [128][64] chunk^=(row&7); staged by
// warps 0-3 via pre-swizzled global source + linear gload_lds.
// FIXED-SCALE softmax: P = exp2(s) directly -- no running max, no rescale.
__global__ __launch_bounds__(320, 2) void k_attn(const u16* __restrict__ Qf,
                                                 const u16* __restrict__ Kf,
                                                 const u16* __restrict__ Vt,
                                                 u16* __restrict__ AttO) {
  __shared__ short Ks[2][8192];  // [64 key][16 chunk][8]
  __shared__ short Vs[2][8192];  // [128 d][8 chunk][8]
  const int h = blockIdx.y;
  const int tid = threadIdx.x;
  const int lane = tid & 63, w = tid >> 6;     // w in 0..4
  const int l31 = lane & 31, hi = lane >> 5;
  const int qrow = blockIdx.x * 160 + w * 32 + l31;

  // Q B-frags: qb[s] = Q[qrow][16s + 8hi + j]
  s16x8 qb[8];
  {
    const u16* qp = Qf + (size_t)qrow * DIM + h * HD + hi * 8;
#pragma unroll
    for (int s = 0; s < 8; ++s) qb[s] = *(const s16x8*)(qp + s * 16);
  }

  f32x16 o[4];
#pragma unroll
  for (int d = 0; d < 4; ++d)
#pragma unroll
    for (int r = 0; r < 16; ++r) o[d][r] = 0.f;
  float sl = 0.f;

  // staging pointers (warps 0..3 only)
  const u16* Kp[4];
  const u16* Vp[4];
  if (w < 4) {
#pragma unroll
    for (int it = 0; it < 4; ++it) {
      const int krow = w * 16 + it * 4 + (lane >> 4);
      const int kch = (lane & 15) ^ (it * 4 + (lane >> 4));
      Kp[it] = Kf + (size_t)krow * DIM + h * HD + kch * 8;
      const int vrow = w * 32 + it * 8 + (lane >> 3);
      const int vch = (lane & 7) ^ (lane >> 3);
      Vp[it] = Vt + (size_t)(h * HD + vrow) * SPAD + vch * 8;
    }
  }
  auto stage = [&](int T, int B) {
    const size_t kof = (size_t)T * KVBLK * DIM;
    const int vof = T * KVBLK;
#pragma unroll
    for (int it = 0; it < 4; ++it) {
      gload16(Kp[it] + kof, &Ks[B][(w * 16 + it * 4) * 128]);
      gload16(Vp[it] + vof, &Vs[B][(w * 32 + it * 8) * 64]);
    }
  };

  if (w < 4) {
    asm volatile("s_waitcnt vmcnt(0)" ::: "memory");
    stage(0, 0);
  }

  for (int t = 0; t < NTILES; ++t) {
    const int b = t & 1;
    if (w < 4) {
      if (t + 1 < NTILES) {
        stage(t + 1, b ^ 1);
        asm volatile("s_waitcnt vmcnt(8)" ::: "memory");
      } else {
        asm volatile("s_waitcnt vmcnt(0)" ::: "memory");
      }
    }
    __builtin_amdgcn_s_barrier();
    __builtin_amdgcn_sched_barrier(0);

    // S^T = K Q  (D[key][q]: col q = l31, row key = CROW(r,hi) per grp of 32)
    f32x16 st[2];
#pragma unroll
    for (int r = 0; r < 16; ++r) { st[0][r] = 0.f; st[1][r] = 0.f; }
    __builtin_amdgcn_s_setprio(1);
#pragma unroll
    for (int grp = 0; grp < 2; ++grp)
#pragma unroll
      for (int s = 0; s < 8; ++s) {
        const s16x8 ka = *(const s16x8*)&Ks[b][(grp * 32 + l31) * 128 +
                                              (((2 * s + hi) ^ (lane & 15)) * 8)];
        st[grp] = __builtin_amdgcn_mfma_f32_32x32x16_bf16(ka, qb[s], st[grp], 0, 0, 0);
      }
    __builtin_amdgcn_s_setprio(0);

    // hoist V B-frags (ds_read latency hides under softmax VALU)
    s16x8 vb[4][4];
#pragma unroll
    for (int s = 0; s < 4; ++s)
#pragma unroll
      for (int d = 0; d < 4; ++d)
        vb[s][d] = *(const s16x8*)&Vs[b][(d * 32 + l31) * 64 +
                                         (((2 * s + hi) ^ (lane & 7)) * 8)];

    if (t == NTILES - 1) {  // keys 3104+16.. invalid: grp1 regs 8..15
#pragma unroll
      for (int r = 8; r < 16; ++r) st[1][r] = NEGBIG;  // exp2 -> 0
    }
    // P = exp2(S): fixed scale, lane-local sums, pack bf16, partner exchange
    unsigned W[16], X[16];
    float p0s = 0.f, p1s = 0.f, p2s = 0.f, p3s = 0.f;
#pragma unroll
    for (int grp = 0; grp < 2; ++grp)
#pragma unroll
      for (int i = 0; i < 8; ++i) {
        const float p0 = exp2f(st[grp][2 * i]);
        const float p1 = exp2f(st[grp][2 * i + 1]);
        if (grp) { p2s += p0; p3s += p1; } else { p0s += p0; p1s += p1; }
        W[grp * 8 + i] = cvtpk(p0, p1);
      }
    sl += (p0s + p1s) + (p2s + p3s);
#pragma unroll
    for (int j = 0; j < 16; ++j) X[j] = __shfl_xor((int)W[j], 32);

    // O += P V
    __builtin_amdgcn_s_setprio(1);
#pragma unroll
    for (int s = 0; s < 4; ++s) {
      const int base = (s >> 1) * 8 + (s & 1) * 4;
      unsigned pw[4];
      pw[0] = hi ? X[base + 2] : W[base + 0];
      pw[1] = hi ? X[base + 3] : W[base + 1];
      pw[2] = hi ? W[base + 2] : X[base + 0];
      pw[3] = hi ? W[base + 3] : X[base + 1];
      const s16x8 pa = *(const s16x8*)pw;
#pragma unroll
      for (int d = 0; d < 4; ++d)
        o[d] = __builtin_amdgcn_mfma_f32_32x32x16_bf16(pa, vb[s][d], o[d], 0, 0, 0);
    }
    __builtin_amdgcn_s_setprio(0);
    __builtin_amdgcn_s_barrier();
    __builtin_amdgcn_sched_barrier(0);
  }

  sl += __shfl_xor(sl, 32);
  const float rs = 1.0f / sl;
#pragma unroll
  for (int r = 0; r < 16; ++r) {
    const float rq = __shfl(rs, CROW(r, hi));
    const int row = blockIdx.x * 160 + w * 32 + CROW(r, hi);
    if (row < SEQ) {
#pragma unroll
      for (int d = 0; d < 4; ++d)
        AttO[(size_t)row * DIM + h * HD + d * 32 + l31] = f2bf(o[d][r] * rq);
    }
  }
}

// ---------------------------------------------------------------------------
extern "C" void kernel_launch(void* const* d_in, const int* in_sizes, int n_in,
                              void* d_out, int out_size, void* d_ws, size_t ws_size,
                              hipStream_t stream) {
  const float* x    = (const float*)d_in[0];
  const float* freqs= (const float*)d_in[1];
  const float* Wq   = (const float*)d_in[2];
  const float* bq   = (const float*)d_in[3];
  const float* gq   = (const float*)d_in[4];
  const float* Wk   = (const float*)d_in[5];
  const float* bk   = (const float*)d_in[6];
  const float* gk   = (const float*)d_in[7];
  const float* Wv   = (const float*)d_in[8];
  const float* bv   = (const float*)d_in[9];
  const float* Wo   = (const float*)d_in[10];
  const float* bo   = (const float*)d_in[11];
  const float* qkfb = (const float*)d_in[12];
  const float* vfb  = (const float*)d_in[13];
  const float* vsb  = (const float*)d_in[14];

  if (ws_size < (size_t)87705600) return;

  char* ws = (char*)d_ws;
  u16*   xb    = (u16*)(ws);               // [3200][1536] bf16
  u16*   Vt    = (u16*)(ws);               // alias: xb dead after QKV GEMM
  u16*   WtAll = (u16*)(ws + 9830400);     // [4608][1536] bf16 (Wq|Wk|Wv)^T
  u16*   WoT   = (u16*)(ws + 23986176);    // [1536][1536] bf16 Wo^T
  float* bcat  = (float*)(ws + 28704768);  // [4608]
  u16*   Pqkv  = (u16*)(ws + 28723200);    // [3200][4608] bf16
  u16*   AttO  = (u16*)(ws + 28723200);    // alias: Pqkv dead after k_post
  u16*   Qf    = (u16*)(ws + 58214400);    // [3200][1536] bf16
  u16*   Kf    = (u16*)(ws + 68044800);    // [3200][1536] bf16
  u16*   Vf    = (u16*)(ws + 77875200);    // [3200][1536] bf16

  k_convert_x<<<4800, 256, 0, stream>>>(x, xb);
  k_transpose_w<<<dim3(48, 48, 4), 256, 0, stream>>>(Wq, Wk, Wv, Wo, WtAll, WoT);
  k_biascat<<<18, 256, 0, stream>>>(bq, bk, bv, bcat);
  k_gemm<1><<<dim3(36, 25), 256, 0, stream>>>(xb, WtAll, bcat, Pqkv, NQKV, DIM, SPAD);
  k_post<<<SEQ, 256, 0, stream>>>(Pqkv, freqs, gq, gk, qkfb, vfb, vsb, Qf, Kf, Vf);
  k_transpose_v<<<dim3(50, 24), 256, 0, stream>>>(Vf, Vt);
  k_attn<<<dim3(20, 12), 320, 0, stream>>>(Qf, Kf, Vt, AttO);
  k_gemm<0><<<dim3(12, 25), 256, 0, stream>>>(AttO, WoT, bo, d_out, DIM, DIM, SEQ);
}